// Round 3
// baseline (77.334 us; speedup 1.0000x reference)
//
#include <hip/hip_runtime.h>
#include <math.h>

// GHM-BCE, fully fused: one kernel (64 blocks x 256 thr = 1 thread/element)
// + one 33KB memset. Counting-sort/CDF order statistics (exact), two manual
// device-scope grid barriers instead of separate kernel launches.

#define N       16384
#define K       4096
#define NBLK    64
#define NTHR    256
#define BPT     (K / NTHR)       // 16 bins scanned per thread
#define DELTA_F 0.1f
#define EPS_F   1e-12f

__device__ __forceinline__ int bucket_of(float v) {
    int b = (int)(v * (float)K);      // monotone; identical at build & query
    b = b < 0 ? 0 : b;
    b = b > (K - 1) ? (K - 1) : b;
    return b;
}

// Device-scope spin barrier. Monotone counter (memset to 0 each launch).
// __threadfence() = agent-scope fence: release (flush) before arrival,
// acquire (invalidate) after — makes plain gs/hist data cross-XCD visible.
__device__ __forceinline__ void grid_bar(int* bar, int phase) {
    __syncthreads();
    if (threadIdx.x == 0) {
        __threadfence();                       // release prior writes
        atomicAdd(bar, 1);
        const int target = phase * (int)gridDim.x;
        while (__hip_atomic_load(bar, __ATOMIC_RELAXED,
                                 __HIP_MEMORY_SCOPE_AGENT) < target) {
            __builtin_amdgcn_s_sleep(1);
        }
        __threadfence();                       // acquire
    }
    __syncthreads();
}

__global__ void __launch_bounds__(NTHR)
ghm_fused(const float* __restrict__ logits, const float* __restrict__ targets,
          int* __restrict__ hist, int* __restrict__ cnt2,
          float* __restrict__ wsum, int* __restrict__ ticket,
          int* __restrict__ bar, float* __restrict__ gs,
          float* __restrict__ out) {
    __shared__ int   hist_l[K];
    __shared__ int   start_l[K];
    __shared__ int   wpart[NTHR / 64];
    __shared__ float sm[NTHR / 64];

    const int tid  = threadIdx.x;
    const int lane = tid & 63;
    const int wid  = tid >> 6;
    const int i    = blockIdx.x * NTHR + tid;     // exactly N threads

    // ---- Phase A+B: per-element math (registers) + global histogram ----
    const float x = logits[i];
    const float t = targets[i];
    const float pred = 1.0f / (1.0f + expf(-x));
    const float gi = fabsf(pred - t);
    const float li = fmaxf(x, 0.0f) - x * t + log1pf(expf(-fabsf(x)));
    const int bi = bucket_of(gi);
    atomicAdd(&hist[bi], 1);                      // hist pre-zeroed by memset

    grid_bar(bar, 1);

    // ---- Phase C: redundant per-block scan of hist -> start[] in LDS ----
    for (int k = tid; k < K; k += NTHR) {
        hist_l[k] = __hip_atomic_load(&hist[k], __ATOMIC_RELAXED,
                                      __HIP_MEMORY_SCOPE_AGENT);
    }
    __syncthreads();

    const int base = tid * BPT;
    int excl[BPT];
    int s = 0;
    #pragma unroll
    for (int k = 0; k < BPT; ++k) { excl[k] = s; s += hist_l[base + k]; }
    // wave64 inclusive scan of per-thread sums
    int scan = s;
    #pragma unroll
    for (int off = 1; off < 64; off <<= 1) {
        int v = __shfl_up(scan, off, 64);
        if (lane >= off) scan += v;
    }
    if (lane == 63) wpart[wid] = scan;
    __syncthreads();
    int wexcl = 0;
    #pragma unroll
    for (int w = 0; w < NTHR / 64; ++w) wexcl += (w < wid) ? wpart[w] : 0;
    const int thr_excl = wexcl + (scan - s);
    #pragma unroll
    for (int k = 0; k < BPT; ++k) start_l[base + k] = thr_excl + excl[k];
    __syncthreads();

    // scatter into globally-sorted-by-bucket array
    const int pos = start_l[bi] + atomicAdd(&cnt2[bi], 1);  // cnt2 pre-zeroed
    gs[pos] = gi;

    grid_bar(bar, 2);

    // ---- Phase D: window count via CDF + exact boundary-bucket scans ----
    const float hiv = gi + DELTA_F;
    const float lov = gi - DELTA_F;
    const int bh = bucket_of(hiv);
    const int bl = bucket_of(lov);

    int cnt = start_l[bh];                        // full buckets < bh
    {
        const int s0 = start_l[bh], e0 = s0 + hist_l[bh];
        for (int p = s0; p < e0; ++p) cnt += (gs[p] <= hiv) ? 1 : 0;
    }
    int below = start_l[bl];
    {
        const int s0 = start_l[bl], e0 = s0 + hist_l[bl];
        for (int p = s0; p < e0; ++p) below += (gs[p] < lov) ? 1 : 0;
    }
    cnt -= below;

    const float GD   = (float)cnt / DELTA_F;
    const float beta = (float)N / (GD + EPS_F);
    float val = beta * li;

    // block reduction
    #pragma unroll
    for (int off = 32; off > 0; off >>= 1) val += __shfl_down(val, off, 64);
    if (lane == 0) sm[wid] = val;
    __syncthreads();
    if (tid == 0) {
        float bs = 0.0f;
        #pragma unroll
        for (int w = 0; w < NTHR / 64; ++w) bs += sm[w];
        atomicAdd(wsum, bs);                      // wsum pre-zeroed
        __threadfence();
        const int done = atomicAdd(ticket, 1);    // ticket pre-zeroed
        if (done == (int)gridDim.x - 1) {
            const float total = atomicAdd(wsum, 0.0f);
            out[0] = total / (float)N;
        }
    }
}

extern "C" void kernel_launch(void* const* d_in, const int* in_sizes, int n_in,
                              void* d_out, int out_size, void* d_ws, size_t ws_size,
                              hipStream_t stream) {
    const float* logits  = (const float*)d_in[0];
    const float* targets = (const float*)d_in[1];
    float* out = (float*)d_out;

    // ws layout: [hist K | cnt2 K | wsum | ticket | bar | pad...] (zeroed) | gs N
    int*   hist   = (int*)d_ws;
    int*   cnt2   = hist + K;
    float* wsum   = (float*)(cnt2 + K);
    int*   ticket = (int*)(wsum + 1);
    int*   bar    = ticket + 1;
    float* gs     = (float*)d_ws + 8448;          // 16B-aligned, past zero region

    hipMemsetAsync(d_ws, 0, 8448 * sizeof(int), stream);
    ghm_fused<<<dim3(NBLK), dim3(NTHR), 0, stream>>>(
        logits, targets, hist, cnt2, wsum, ticket, bar, gs, out);
}